// Round 2
// baseline (176.116 us; speedup 1.0000x reference)
//
#include <hip/hip_runtime.h>

typedef _Float16 f16;
typedef _Float16 f16x8 __attribute__((ext_vector_type(8)));
typedef float    f32x16 __attribute__((ext_vector_type(16)));

#define NV      2000
#define RR      128
#define KM1     30
#define KKOUT   31
#define NQ      900          // KM1*KM1
#define QQ      961          // KKOUT*KKOUT
#define COV_OFF 62000        // NV*KKOUT

// ws layout:
//   B5 at 0: [qt(29)][kz(4)][stage t(16)][slot(9)][1KB frag] = 17,104,896 B
//     stage (qt,kz,t) holds i_a = kz*16+t (slots 0..7-kz, s=kz..7) then
//     i_b = (7-kz)*16+t (slots 8-kz..8, s=7-kz..7); frag: lane(kq,l31) elem d
//     = Bs[i, j=s*16+kq*8+d, q=qt*32+l31] (f16), zero for j<i, diag 1x.
//   Xh at B5_BYTES: f16 X^T [v 0..2047][r 0..127]
#define B5_BYTES 17104896
#define XH_BYTES 524288

#define PERM_BLKS  3840
#define XC1_BLKS   128
#define ZERO_BLKS  1877
#define MEAN_BLKS  248
#define PREP_GRID  (PERM_BLKS + XC1_BLKS + ZERO_BLKS + MEAN_BLKS)

// ---------------------------------------------------------------------------
// Fused prep: symmetrize+permute Cov -> B5; Xh cast; zero cov + 0.5 diag;
// exact fp32 mean. Roles by blockIdx range.  (unchanged this round)
// ---------------------------------------------------------------------------
__global__ void prep_kernel(const float* __restrict__ Xi,
                            const float* __restrict__ Wm,
                            const float* __restrict__ cov,
                            const float* __restrict__ Cmu,
                            f16* __restrict__ B5,
                            f16* __restrict__ Xh,
                            float* __restrict__ outm,
                            float* __restrict__ oc) {
    __shared__ float rowS[3840];
    int b = blockIdx.x, tid = threadIdx.x;
    if (b < PERM_BLKS) {
        int i = b / 30, k = b - i * 30;
        int g = i >> 4;
        int j0 = g << 4;
        int W = 128 - j0;
        int lo = (i - j0) * 30;                   // rowS[0,lo) = 0 (j<i pad)
        const float* src = cov + (size_t)b * 3840 + j0 * 30;
        for (int t = tid; t < W * 30; t += 256)
            rowS[t] = (t >= lo) ? src[t] : 0.f;
        __syncthreads();
        // symmetrize: rowS[(j-j0)*30+l] += C[(j*30+k),(i*30+l)], j in (i,128)
        int n2 = (127 - i) * 15;                  // float2 pairs
        for (int idx = tid; idx < n2; idx += 256) {
            int j = i + 1 + idx / 15;
            int p = idx - (j - i - 1) * 15;
            const float2 v2 = *(const float2*)(cov + (size_t)(j * 30 + k) * 3840 + i * 30 + 2 * p);
            rowS[(j - j0) * 30 + 2 * p]     += v2.x;
            rowS[(j - j0) * 30 + 2 * p + 1] += v2.y;
        }
        __syncthreads();
        int t_st = i & 15;
        int nOct = W >> 3;
        for (int it = tid; it < nOct * 30; it += 256) {
            int oct = it / 30, l = it - oct * 30;
            int j = j0 + oct * 8;
            int s = j >> 4, kq = (j >> 3) & 1;
            int q = k * 30 + l, qt = q >> 5, l31 = q & 31;
            int kz, slot;
            if (g < 4) { kz = g;     slot = s - g; }
            else       { kz = 7 - g; slot = s + 1; }
            f16 vals[8];
#pragma unroll
            for (int d = 0; d < 8; ++d) vals[d] = (f16)rowS[(j + d - j0) * 30 + l];
            f16* dst = B5 + ((((size_t)(qt * 4 + kz) * 16 + t_st) * 9 + slot) << 9)
                          + (kq * 32 + l31) * 8;
            *(uint4*)dst = *(uint4*)vals;
        }
        return;
    }
    b -= PERM_BLKS;
    if (b < XC1_BLKS) {                           // Xh [v][r]
        int t = b * 256 + tid;
        int v = t & 2047, rc = t >> 11;
        f16 vals[8];
#pragma unroll
        for (int d = 0; d < 8; ++d) {
            float x = (v < NV) ? Xi[(rc * 8 + d) * NV + v] : 0.f;
            vals[d] = (f16)x;
        }
        *(uint4*)(Xh + (size_t)v * 128 + rc * 8) = *(uint4*)vals;
        return;
    }
    b -= XC1_BLKS;
    if (b < ZERO_BLKS) {
        size_t idx = ((size_t)b * 256 + tid) * 4;
        if (idx < (size_t)NV * QQ) {
            unsigned rem = (unsigned)(idx % QQ);
            float4 zv;
            zv.x = (rem == 0u)   ? 0.5f : 0.f;
            zv.y = (rem == 960u) ? 0.5f : 0.f;
            zv.z = (rem == 959u) ? 0.5f : 0.f;
            zv.w = (rem == 958u) ? 0.5f : 0.f;
            *(float4*)(oc + idx) = zv;
        }
        return;
    }
    b -= ZERO_BLKS;
    int t2 = b * 256 + tid;
    int c = t2 >> 11, v = t2 & 2047;
    if (v >= NV || c >= KKOUT) return;
    if (c == 0) { outm[(size_t)v * KKOUT] = Cmu[v]; return; }
    float acc = 0.f;
    const float* w = Wm + (c - 1);
#pragma unroll 8
    for (int i = 0; i < RR; ++i)
        acc = fmaf(Xi[i * NV + v], w[i * KM1], acc);
    outm[(size_t)v * KKOUT + c] = acc;
}

// ---------------------------------------------------------------------------
// GEMM body, KZ compile-time. Block: 4 waves x (128v x 32q) = 512v x 32q.
// No LDS, no barriers. Each lane's B operand is exactly its own 16B of
// the 1KB frag (lane*8 f16), so it is loaded global->VGPR directly
// (global_load_dwordx4, fully coalesced; the 4 waves of a block read
// identical addresses -> L1 serves the reuse; per-XCD slice ~2.1MB stays
// L2-resident via the swizzle). Fully-unrolled 16x9 load stream lets the
// compiler software-pipeline with counted vmcnt -- no barrier drain.
// xi scalars pulled out of resident xj regs via __shfl; A-operand uses
// scalar-broadcast v_pk_mul (xj * xA) instead of materialized f16x8 splats
// (saves ~24 VGPR + 8 VALU/stage) to keep KZ=0 under the 256-reg budget.
// ---------------------------------------------------------------------------
template<int KZ>
__device__ __forceinline__ void gemm_body(const f16* __restrict__ B5,
                                          const f16* __restrict__ Xh,
                                          float* __restrict__ out_cov,
                                          int qt, int y) {
    constexpr int NA = 8 - KZ, NB = 1 + KZ, NS = 8 - KZ, UB = 7 - 2 * KZ;
    const int tid = threadIdx.x, lane = tid & 63, w = tid >> 6;
    const int l31 = lane & 31, kq = lane >> 5;
    const int v0 = y * 512 + w * 128;
    const int vr = v0 + l31;

    // xj[fm][u]: x[vr+fm*32, (KZ+u)*16 + kq*8 + d]  (covers all slots' s)
    f16x8 xj[4][NS];
#pragma unroll
    for (int fm = 0; fm < 4; ++fm)
#pragma unroll
        for (int u = 0; u < NS; ++u)
            xj[fm][u] = *(const f16x8*)(Xh + (size_t)(vr + fm * 32) * 128 + (KZ + u) * 16 + kq * 8);

    const f16* gbase = B5 + ((size_t)(qt * 4 + KZ) * 16) * 4608 + lane * 8;

    f32x16 acc[4] = {};

#pragma unroll
    for (int t = 0; t < 16; ++t) {
        // B operands for this stage: 9 x 16B per lane, direct global->reg
        f16x8 bfv[9];
#pragma unroll
        for (int m = 0; m < 9; ++m)
            bfv[m] = *(const f16x8*)(gbase + (size_t)t * 4608 + m * 512);

        // xi broadcasts: i_a = KZ*16+t (from xj[.][0]), i_b = (7-KZ)*16+t (xj[.][UB])
        const int srcl = l31 + ((t >> 3) << 5);
        f16 xA[4], xB[4];
#pragma unroll
        for (int fm = 0; fm < 4; ++fm) {
            unsigned short ha = __builtin_bit_cast(unsigned short, (f16)xj[fm][0][t & 7]);
            unsigned short hb = __builtin_bit_cast(unsigned short, (f16)xj[fm][UB][t & 7]);
            int pa = __shfl((int)ha, srcl, 64);
            int pb = __shfl((int)hb, srcl, 64);
            xA[fm] = __builtin_bit_cast(f16, (unsigned short)pa);
            xB[fm] = __builtin_bit_cast(f16, (unsigned short)pb);
        }
#pragma unroll
        for (int m = 0; m < NA; ++m) {           // role-A slots: s = KZ+m
#pragma unroll
            for (int fm = 0; fm < 4; ++fm)
                acc[fm] = __builtin_amdgcn_mfma_f32_32x32x16_f16(xj[fm][m] * xA[fm], bfv[m], acc[fm], 0, 0, 0);
        }
#pragma unroll
        for (int m2 = 0; m2 < NB; ++m2) {        // role-B slots: s = 7-KZ+m2
#pragma unroll
            for (int fm = 0; fm < 4; ++fm)
                acc[fm] = __builtin_amdgcn_mfma_f32_32x32x16_f16(xj[fm][UB + m2] * xB[fm], bfv[NA + m2], acc[fm], 0, 0, 0);
        }
    }

    // epilogue: C/D col=lane&31 (q), row=4*kq+(reg&3)+8*(reg>>2) (v)
    const int q = qt * 32 + l31;
    if (q >= NQ) return;
    const int kk = q / 30, ll = q - kk * 30;
    float* cb = out_cov + (kk + 1) * KKOUT + (ll + 1);
#pragma unroll
    for (int fm = 0; fm < 4; ++fm) {
        int vb = v0 + fm * 32 + 4 * kq;
#pragma unroll
        for (int r = 0; r < 16; ++r) {
            int v = vb + (r & 3) + 8 * (r >> 2);
            if (v < NV) atomicAdd(cb + (size_t)v * QQ, acc[fm][r]);
        }
    }
}

// ---------------------------------------------------------------------------
// Grid 480 = 120 slices (qt,kz) x 4 y; swizzle: slice's 4 y-blocks share one
// XCD (per-XCD B working set ~2.1 MB -> L2-resident, fetched once).
// ---------------------------------------------------------------------------
__launch_bounds__(256, 2)
__global__ void gemm5_kernel(const f16* __restrict__ B5,
                             const f16* __restrict__ Xh,
                             float* __restrict__ out_cov) {
    const int bid = blockIdx.x;
    const int xcd = bid & 7, base = bid >> 3;
    const int y = base & 3, s3 = base >> 2;      // s3 0..14
    const int S = s3 * 8 + xcd;                  // slice 0..119
    const int qt = S >> 2, kz = S & 3;
    if (qt >= 29) return;
    switch (kz) {
        case 0:  gemm_body<0>(B5, Xh, out_cov, qt, y); break;
        case 1:  gemm_body<1>(B5, Xh, out_cov, qt, y); break;
        case 2:  gemm_body<2>(B5, Xh, out_cov, qt, y); break;
        default: gemm_body<3>(B5, Xh, out_cov, qt, y); break;
    }
}

// ---------------------------------------------------------------------------
extern "C" void kernel_launch(void* const* d_in, const int* in_sizes, int n_in,
                              void* d_out, int out_size, void* d_ws, size_t ws_size,
                              hipStream_t stream) {
    const float* Xi  = (const float*)d_in[0];   // (128, 2000)
    const float* Wm  = (const float*)d_in[1];   // (3840, 1)
    const float* Cov = (const float*)d_in[2];   // (3840, 3840)
    const float* Cmu = (const float*)d_in[3];   // (2000, 1)
    float* out      = (float*)d_out;
    float* out_mean = out;                       // (2000, 31)
    float* out_cov  = out + COV_OFF;             // (2000, 31, 31)
    f16* B5 = (f16*)d_ws;
    f16* Xh = (f16*)((char*)d_ws + B5_BYTES);

    prep_kernel <<<PREP_GRID, 256, 0, stream>>>(Xi, Wm, Cov, Cmu, B5, Xh,
                                                out_mean, out_cov);
    gemm5_kernel<<<480, 256, 0, stream>>>(B5, Xh, out_cov);
}

// Round 3
// 155.626 us; speedup vs baseline: 1.1317x; 1.1317x over previous
//
#include <hip/hip_runtime.h>

typedef _Float16 f16;
typedef _Float16 f16x8 __attribute__((ext_vector_type(8)));
typedef float    f32x16 __attribute__((ext_vector_type(16)));

#define NV      2000
#define RR      128
#define KM1     30
#define KKOUT   31
#define NQ      900          // KM1*KM1
#define QQ      961          // KKOUT*KKOUT
#define COV_OFF 62000        // NV*KKOUT

// ws layout:
//   B5 at 0: [qt(29)][kz(4)][stage t(16)][slot(9)][1KB frag] = 17,104,896 B
//     stage (qt,kz,t) holds i_a = kz*16+t (slots 0..7-kz, s=kz..7) then
//     i_b = (7-kz)*16+t (slots 8-kz..8, s=7-kz..7); frag: lane(kq,l31) elem d
//     = Bs[i, j=s*16+kq*8+d, q=qt*32+l31] (f16), zero for j<i, diag 1x.
//   Xh at B5_BYTES: f16 X^T [v 0..2047][r 0..127]
#define B5_BYTES 17104896
#define XH_BYTES 524288

#define PERM_BLKS  3840
#define XC1_BLKS   128
#define ZERO_BLKS  1877
#define MEAN_BLKS  248
#define PREP_GRID  (PERM_BLKS + XC1_BLKS + ZERO_BLKS + MEAN_BLKS)

// ---------------------------------------------------------------------------
// Fused prep: symmetrize+permute Cov -> B5; Xh cast; zero cov + 0.5 diag;
// exact fp32 mean. Roles by blockIdx range.  (unchanged this round)
// ---------------------------------------------------------------------------
__global__ void prep_kernel(const float* __restrict__ Xi,
                            const float* __restrict__ Wm,
                            const float* __restrict__ cov,
                            const float* __restrict__ Cmu,
                            f16* __restrict__ B5,
                            f16* __restrict__ Xh,
                            float* __restrict__ outm,
                            float* __restrict__ oc) {
    __shared__ float rowS[3840];
    int b = blockIdx.x, tid = threadIdx.x;
    if (b < PERM_BLKS) {
        int i = b / 30, k = b - i * 30;
        int g = i >> 4;
        int j0 = g << 4;
        int W = 128 - j0;
        int lo = (i - j0) * 30;                   // rowS[0,lo) = 0 (j<i pad)
        const float* src = cov + (size_t)b * 3840 + j0 * 30;
        for (int t = tid; t < W * 30; t += 256)
            rowS[t] = (t >= lo) ? src[t] : 0.f;
        __syncthreads();
        // symmetrize: rowS[(j-j0)*30+l] += C[(j*30+k),(i*30+l)], j in (i,128)
        int n2 = (127 - i) * 15;                  // float2 pairs
        for (int idx = tid; idx < n2; idx += 256) {
            int j = i + 1 + idx / 15;
            int p = idx - (j - i - 1) * 15;
            const float2 v2 = *(const float2*)(cov + (size_t)(j * 30 + k) * 3840 + i * 30 + 2 * p);
            rowS[(j - j0) * 30 + 2 * p]     += v2.x;
            rowS[(j - j0) * 30 + 2 * p + 1] += v2.y;
        }
        __syncthreads();
        int t_st = i & 15;
        int nOct = W >> 3;
        for (int it = tid; it < nOct * 30; it += 256) {
            int oct = it / 30, l = it - oct * 30;
            int j = j0 + oct * 8;
            int s = j >> 4, kq = (j >> 3) & 1;
            int q = k * 30 + l, qt = q >> 5, l31 = q & 31;
            int kz, slot;
            if (g < 4) { kz = g;     slot = s - g; }
            else       { kz = 7 - g; slot = s + 1; }
            f16 vals[8];
#pragma unroll
            for (int d = 0; d < 8; ++d) vals[d] = (f16)rowS[(j + d - j0) * 30 + l];
            f16* dst = B5 + ((((size_t)(qt * 4 + kz) * 16 + t_st) * 9 + slot) << 9)
                          + (kq * 32 + l31) * 8;
            *(uint4*)dst = *(uint4*)vals;
        }
        return;
    }
    b -= PERM_BLKS;
    if (b < XC1_BLKS) {                           // Xh [v][r]
        int t = b * 256 + tid;
        int v = t & 2047, rc = t >> 11;
        f16 vals[8];
#pragma unroll
        for (int d = 0; d < 8; ++d) {
            float x = (v < NV) ? Xi[(rc * 8 + d) * NV + v] : 0.f;
            vals[d] = (f16)x;
        }
        *(uint4*)(Xh + (size_t)v * 128 + rc * 8) = *(uint4*)vals;
        return;
    }
    b -= XC1_BLKS;
    if (b < ZERO_BLKS) {
        size_t idx = ((size_t)b * 256 + tid) * 4;
        if (idx < (size_t)NV * QQ) {
            unsigned rem = (unsigned)(idx % QQ);
            float4 zv;
            zv.x = (rem == 0u)   ? 0.5f : 0.f;
            zv.y = (rem == 960u) ? 0.5f : 0.f;
            zv.z = (rem == 959u) ? 0.5f : 0.f;
            zv.w = (rem == 958u) ? 0.5f : 0.f;
            *(float4*)(oc + idx) = zv;
        }
        return;
    }
    b -= ZERO_BLKS;
    int t2 = b * 256 + tid;
    int c = t2 >> 11, v = t2 & 2047;
    if (v >= NV || c >= KKOUT) return;
    if (c == 0) { outm[(size_t)v * KKOUT] = Cmu[v]; return; }
    float acc = 0.f;
    const float* w = Wm + (c - 1);
#pragma unroll 8
    for (int i = 0; i < RR; ++i)
        acc = fmaf(Xi[i * NV + v], w[i * KM1], acc);
    outm[(size_t)v * KKOUT + c] = acc;
}

// ---------------------------------------------------------------------------
// load the 9 slot-fragments of one stage (this lane's 16B of each 1KB frag)
// ---------------------------------------------------------------------------
__device__ __forceinline__ void load9(f16x8 (&b)[9], const f16* p) {
#pragma unroll
    for (int m = 0; m < 9; ++m)
        b[m] = *(const f16x8*)(p + m * 512);
}

// ---------------------------------------------------------------------------
// one stage of one kz-section: 9 slots x 2 fm MFMAs.
// xj[u] holds x[v, u*16 + kq*8 + d] for s=u (full s range 0..7, merged kz).
// role-A slots m: s = KZ+m, scalar xA = x[v, KZ*16+t];
// role-B slots m2: s = 7-KZ+m2, scalar xB = x[v, (7-KZ)*16+t].
// t is compile-time (fully unrolled) so element extracts are static.
// ---------------------------------------------------------------------------
template<int KZ>
__device__ __forceinline__ void stage_compute(int t, int l31,
                                              const f16x8 (&bv)[9],
                                              const f16x8 (&xj)[2][8],
                                              f32x16 (&acc)[2]) {
    constexpr int NA = 8 - KZ, NB = 1 + KZ;
    const int srcl = l31 + ((t >> 3) << 5);
    f16 xA[2], xB[2];
#pragma unroll
    for (int fm = 0; fm < 2; ++fm) {
        unsigned short ha = __builtin_bit_cast(unsigned short, (f16)xj[fm][KZ][t & 7]);
        unsigned short hb = __builtin_bit_cast(unsigned short, (f16)xj[fm][7 - KZ][t & 7]);
        int pa = __shfl((int)ha, srcl, 64);
        int pb = __shfl((int)hb, srcl, 64);
        xA[fm] = __builtin_bit_cast(f16, (unsigned short)pa);
        xB[fm] = __builtin_bit_cast(f16, (unsigned short)pb);
    }
#pragma unroll
    for (int m = 0; m < NA; ++m)
#pragma unroll
        for (int fm = 0; fm < 2; ++fm)
            acc[fm] = __builtin_amdgcn_mfma_f32_32x32x16_f16(xj[fm][KZ + m] * xA[fm], bv[m], acc[fm], 0, 0, 0);
#pragma unroll
    for (int m2 = 0; m2 < NB; ++m2)
#pragma unroll
        for (int fm = 0; fm < 2; ++fm)
            acc[fm] = __builtin_amdgcn_mfma_f32_32x32x16_f16(xj[fm][7 - KZ + m2] * xB[fm], bv[NA + m2], acc[fm], 0, 0, 0);
}

// ---------------------------------------------------------------------------
// one kz-section: 16 stages, ping-pong cur/nxt (static indices, no scratch).
// Entry: cur = stage KZ*16 loaded, gs -> stage KZ*16+1.
// Exit:  cur = stage (KZ+1)*16 loaded, gs -> next (contiguous in B5).
// ---------------------------------------------------------------------------
template<int KZ>
__device__ __forceinline__ void kz_section(const f16*& gs,
                                           f16x8 (&cur)[9], f16x8 (&nxt)[9],
                                           const f16x8 (&xj)[2][8],
                                           f32x16 (&acc)[2], int l31) {
#pragma unroll
    for (int tt = 0; tt < 8; ++tt) {
        load9(nxt, gs); gs += 4608;              // stage 2tt+1
        stage_compute<KZ>(2 * tt, l31, cur, xj, acc);
        load9(cur, gs); gs += 4608;              // stage 2tt+2
        stage_compute<KZ>(2 * tt + 1, l31, nxt, xj, acc);
    }
}

// ---------------------------------------------------------------------------
// Merged-kz GEMM. Grid 232 = 8 xcd x 29; block = 4 waves x (64v x 32q),
// fm=2 -> 256 v per block, 8 y-groups x 29 qt.
// All 4 kz-slices (the full i-range) accumulate in-register -> plain stores,
// NO atomics. No LDS, no barriers: B read global->VGPR (lane*16B of each
// frag, coalesced 1KB/wave; 4 waves share via L1). Stage stream is
// contiguous across kz so the cur/nxt pipeline never drains.
// XCD map: p=(bid&7)*29+(bid>>3) gives each XCD a contiguous ~4.6-qt span
// (~1.4MB B working set, L2-resident).
// Register budget (the R2 lesson): xj 64 + cur/nxt 72 + acc 32 + addr ~20
// ~= 190 unified; launch_bounds(256,1) lifts the 128-VGPR cap -> no spill.
// Final nxt-load of sec<3> overruns into Xh region (harmless, in-ws).
// ---------------------------------------------------------------------------
__launch_bounds__(256, 1)
__global__ void gemm6_kernel(const f16* __restrict__ B5,
                             const f16* __restrict__ Xh,
                             float* __restrict__ out_cov) {
    const int bid = blockIdx.x;
    const int p = (bid & 7) * 29 + (bid >> 3);   // 0..231
    const int qt = p >> 3, y = p & 7;            // qt 0..28, y 0..7
    const int tid = threadIdx.x, lane = tid & 63, w = tid >> 6;
    const int l31 = lane & 31, kq = lane >> 5;
    const int v0 = y * 256 + w * 64;
    const int vr = v0 + l31;

    // xj[fm][u]: x[vr+fm*32, u*16 + kq*8 + d], full s range (merged kz)
    f16x8 xj[2][8];
#pragma unroll
    for (int fm = 0; fm < 2; ++fm)
#pragma unroll
        for (int u = 0; u < 8; ++u)
            xj[fm][u] = *(const f16x8*)(Xh + (size_t)(vr + fm * 32) * 128 + u * 16 + kq * 8);

    const f16* gbase = B5 + (size_t)qt * 64 * 4608 + lane * 8;

    f16x8 cur[9], nxt[9];
    load9(cur, gbase);                           // stage 0
    const f16* gs = gbase + 4608;

    f32x16 acc[2] = {};
    kz_section<0>(gs, cur, nxt, xj, acc, l31);
    kz_section<1>(gs, cur, nxt, xj, acc, l31);
    kz_section<2>(gs, cur, nxt, xj, acc, l31);
    kz_section<3>(gs, cur, nxt, xj, acc, l31);

    // epilogue: plain stores (out[v][q] complete: all i covered in-block).
    // C/D: col=l31 (q), row = 4*kq + (r&3) + 8*(r>>2) within fm's 32-v group.
    const int q = qt * 32 + l31;
    if (q >= NQ) return;
    const int kk = q / 30, ll = q - kk * 30;
    float* cb = out_cov + (kk + 1) * KKOUT + (ll + 1);
#pragma unroll
    for (int fm = 0; fm < 2; ++fm) {
        int vb = v0 + fm * 32 + 4 * kq;
#pragma unroll
        for (int r = 0; r < 16; ++r) {
            int v = vb + (r & 3) + 8 * (r >> 2);
            if (v < NV) cb[(size_t)v * QQ] = acc[fm][r];
        }
    }
}

// ---------------------------------------------------------------------------
extern "C" void kernel_launch(void* const* d_in, const int* in_sizes, int n_in,
                              void* d_out, int out_size, void* d_ws, size_t ws_size,
                              hipStream_t stream) {
    const float* Xi  = (const float*)d_in[0];   // (128, 2000)
    const float* Wm  = (const float*)d_in[1];   // (3840, 1)
    const float* Cov = (const float*)d_in[2];   // (3840, 3840)
    const float* Cmu = (const float*)d_in[3];   // (2000, 1)
    float* out      = (float*)d_out;
    float* out_mean = out;                       // (2000, 31)
    float* out_cov  = out + COV_OFF;             // (2000, 31, 31)
    f16* B5 = (f16*)d_ws;
    f16* Xh = (f16*)((char*)d_ws + B5_BYTES);

    prep_kernel <<<PREP_GRID, 256, 0, stream>>>(Xi, Wm, Cov, Cmu, B5, Xh,
                                                out_mean, out_cov);
    gemm6_kernel<<<232, 256, 0, stream>>>(B5, Xh, out_cov);
}